// Round 1
// baseline (506.838 us; speedup 1.0000x reference)
//
#include <hip/hip_runtime.h>

#define B    32
#define S    1024
#define D    512
#define D2   1024
#define D5   2560
#define V    50000
#define VO   49000
#define NCH  14          // vocab chunks for kC finalize (14*3500 = 49000)
#define CHW  3500
#define NCHV 766         // gemm_vocab v-tiles (766*64 = 49024 >= 49000)

__device__ __forceinline__ float fast_tanh(float x){
    float e = __expf(2.0f * x);
    return 1.0f - __fdividef(2.0f, e + 1.0f);
}

// gemm_nt: parts[(ks*B + b)*Nreal + v] = sum_{k in slice ks} W[v][k] * X(b,k)
// X(b,k) = (k < xsplit ? xa[b*xstra+k] : xb[b*xstrb+k-xsplit])
// v-tile 256, 32 b, 16-k inner tiles, register-prefetch pipeline. No atomics.
__global__ __launch_bounds__(256) void gemm_nt(
    const float* __restrict__ W, int Nreal, int K,
    const float* __restrict__ xa, const float* __restrict__ xb,
    int xsplit, int xstra, int xstrb,
    float* __restrict__ parts, int KS)
{
    __shared__ float sW[16 * 260];
    __shared__ float sX[16 * 32];
    const int t    = threadIdx.x;
    const int lane = t & 63;
    const int v0   = blockIdx.x * 256;
    const int ks0  = blockIdx.y * KS;
    const int b0   = (t >> 6) * 8;

    const int vrow  = v0 + t;
    const size_t wb = (size_t)((vrow < Nreal) ? vrow : (Nreal - 1)) * K;

    float acc[4][8];
    #pragma unroll
    for (int i = 0; i < 4; ++i)
        #pragma unroll
        for (int j = 0; j < 8; ++j) acc[i][j] = 0.f;

    const int  xbi  = t >> 2;
    const int  xq   = t & 3;
    const bool xact = t < 128;

    float4 wreg[4];
    float  xreg[4];
    #pragma unroll
    for (int e = 0; e < 4; ++e) wreg[e] = *(const float4*)&W[wb + ks0 + e * 4];
    if (xact){
        #pragma unroll
        for (int e = 0; e < 4; ++e){
            int k = ks0 + xq * 4 + e;
            xreg[e] = (k < xsplit) ? xa[xbi * xstra + k] : xb[xbi * xstrb + (k - xsplit)];
        }
    }

    const int ntiles = KS >> 4;
    for (int tl = 0; tl < ntiles; ++tl){
        #pragma unroll
        for (int e = 0; e < 4; ++e){
            sW[(e * 4 + 0) * 260 + t] = wreg[e].x;
            sW[(e * 4 + 1) * 260 + t] = wreg[e].y;
            sW[(e * 4 + 2) * 260 + t] = wreg[e].z;
            sW[(e * 4 + 3) * 260 + t] = wreg[e].w;
        }
        if (xact){
            #pragma unroll
            for (int e = 0; e < 4; ++e) sX[(xq * 4 + e) * 32 + xbi] = xreg[e];
        }
        __syncthreads();
        if (tl + 1 < ntiles){
            int kn = ks0 + (tl + 1) * 16;
            #pragma unroll
            for (int e = 0; e < 4; ++e) wreg[e] = *(const float4*)&W[wb + kn + e * 4];
            if (xact){
                #pragma unroll
                for (int e = 0; e < 4; ++e){
                    int k = kn + xq * 4 + e;
                    xreg[e] = (k < xsplit) ? xa[xbi * xstra + k] : xb[xbi * xstrb + (k - xsplit)];
                }
            }
        }
        #pragma unroll
        for (int kk = 0; kk < 16; ++kk){
            const float4 w0 = *(const float4*)&sW[kk * 260 + lane * 4];
            const float4 x0 = *(const float4*)&sX[kk * 32 + b0];
            const float4 x1 = *(const float4*)&sX[kk * 32 + b0 + 4];
            const float wv[4] = {w0.x, w0.y, w0.z, w0.w};
            const float xv[8] = {x0.x, x0.y, x0.z, x0.w, x1.x, x1.y, x1.z, x1.w};
            #pragma unroll
            for (int i = 0; i < 4; ++i)
                #pragma unroll
                for (int j = 0; j < 8; ++j)
                    acc[i][j] += wv[i] * xv[j];
        }
        __syncthreads();
    }
    const int vbase = v0 + lane * 4;
    if (vbase < Nreal){
        const size_t pb = (size_t)blockIdx.y * B;
        #pragma unroll
        for (int j = 0; j < 8; ++j){
            float4 o = make_float4(acc[0][j], acc[1][j], acc[2][j], acc[3][j]);
            *(float4*)&parts[(pb + b0 + j) * (size_t)Nreal + vbase] = o;
        }
    }
}

// reduce parts over splits (+ optional per-row bias, row length = bmask+1 pow2)
__global__ void kreduce(const float* __restrict__ parts, float* __restrict__ out,
                        int n, int nsplit, const float* __restrict__ bias, int bmask){
    int i = blockIdx.x * 256 + threadIdx.x;
    if (i < n){
        float s = 0.f;
        for (int p = 0; p < nsplit; ++p) s += parts[(size_t)p * n + i];
        if (bias) s += bias[i & bmask];
        out[i] = s;
    }
}

// K2a: attn logit[b][s] = sum_d tanh(enc1[b][s][d] + dec_op1[b][d] + b_dec[d]) * w_attn[d]
// Also emits per-(b,tile) masked-softmax partials over its 16 rows:
//   pm = max(l) (unmasked), ps = sum mask * exp(l - pm)
__global__ void k2a_logit(const float* __restrict__ enc1, const float* __restrict__ dop1,
                          const float* __restrict__ bdec, const float* __restrict__ wat,
                          const int* __restrict__ src,
                          float* __restrict__ lg, float* __restrict__ pm,
                          float* __restrict__ ps){
    int b = blockIdx.x;
    int wave = threadIdx.x >> 6, lane = threadIdx.x & 63;
    int s0 = blockIdx.y * 16 + wave * 4;
    __shared__ float sd[D2], sw[D2];
    __shared__ float slog[16];
    for (int i = threadIdx.x; i < D2; i += 256){
        sd[i] = dop1[b * D2 + i] + bdec[i];
        sw[i] = wat[i];
    }
    __syncthreads();
    const float4* sd4 = (const float4*)sd;
    const float4* sw4 = (const float4*)sw;
    for (int r = 0; r < 4; ++r){
        int s = s0 + r;
        const float4* row = (const float4*)(enc1 + ((size_t)b * S + s) * D2);
        float acc = 0.f;
        #pragma unroll
        for (int i = 0; i < 4; ++i){
            int k4 = i * 64 + lane;
            float4 e = row[k4]; float4 dv = sd4[k4]; float4 wv = sw4[k4];
            acc += fast_tanh(e.x + dv.x) * wv.x + fast_tanh(e.y + dv.y) * wv.y
                 + fast_tanh(e.z + dv.z) * wv.z + fast_tanh(e.w + dv.w) * wv.w;
        }
        #pragma unroll
        for (int off = 32; off > 0; off >>= 1) acc += __shfl_down(acc, off, 64);
        if (lane == 0){
            lg[b * S + s] = acc;
            slog[wave * 4 + r] = acc;
        }
    }
    __syncthreads();
    if (threadIdx.x == 0){
        int sbase = blockIdx.y * 16;
        float m = -1e30f;
        #pragma unroll
        for (int i = 0; i < 16; ++i) m = fmaxf(m, slog[i]);
        float sum = 0.f;
        #pragma unroll
        for (int i = 0; i < 16; ++i){
            bool keep = src[b * S + sbase + i] != 0;
            sum += keep ? __expf(slog[i] - m) : 0.f;
        }
        pm[b * 64 + blockIdx.y] = m;
        ps[b * 64 + blockIdx.y] = sum;
    }
}

// K2c: combine 64 tile stats -> masked softmax attn (output 1) for this block's
// 32 s values, then context partials over s-splits. Replaces old k2b + k2c.
__global__ void k2c_attn_ctx(const float* __restrict__ enc, const float* __restrict__ lg,
                             const int* __restrict__ src, const float* __restrict__ pm,
                             const float* __restrict__ ps,
                             float* __restrict__ attn, float* __restrict__ part){
    int b = blockIdx.x, sp = blockIdx.y, t = threadIdx.x;
    __shared__ float sa[32];
    __shared__ float sMS[2];
    if (t < 64){
        float m = pm[b * 64 + t];
        float s = ps[b * 64 + t];
        float M = m;
        #pragma unroll
        for (int off = 1; off < 64; off <<= 1) M = fmaxf(M, __shfl_xor(M, off, 64));
        float sv = s * __expf(m - M);
        #pragma unroll
        for (int off = 1; off < 64; off <<= 1) sv += __shfl_xor(sv, off, 64);
        if (t == 0){ sMS[0] = M; sMS[1] = sv; }
    }
    __syncthreads();
    float M   = sMS[0];
    float inv = 1.0f / sMS[1];
    if (t < 32){
        int s = sp * 32 + t;
        float l = lg[b * S + s];
        bool keep = src[b * S + s] != 0;
        float a = keep ? __expf(l - M) * inv : 0.f;
        attn[b * S + s] = a;
        sa[t] = a;
    }
    __syncthreads();
    const float4* base = (const float4*)(enc + ((size_t)b * S + sp * 32) * D2);
    float4 acc = make_float4(0.f, 0.f, 0.f, 0.f);
    #pragma unroll 4
    for (int s = 0; s < 32; ++s){
        float a = sa[s];
        float4 e = base[s * (D2 / 4) + t];
        acc.x += a * e.x; acc.y += a * e.y; acc.z += a * e.z; acc.w += a * e.w;
    }
    ((float4*)(part + ((size_t)(b * 32 + sp)) * D2))[t] = acc;
}

// K2d: reduce partials + batchnorm -> context (output 2)
__global__ void k2d_ctxbn(const float* __restrict__ part, const float* __restrict__ gamma,
                          const float* __restrict__ beta, const float* __restrict__ mean,
                          const float* __restrict__ var, float* __restrict__ ctx){
    int b = blockIdx.x, t = threadIdx.x;
    float4 acc = make_float4(0.f, 0.f, 0.f, 0.f);
    for (int sp = 0; sp < 32; ++sp){
        float4 p = ((const float4*)(part + ((size_t)(b * 32 + sp)) * D2))[t];
        acc.x += p.x; acc.y += p.y; acc.z += p.z; acc.w += p.w;
    }
    float4 g  = ((const float4*)gamma)[t];
    float4 be = ((const float4*)beta)[t];
    float4 mn = ((const float4*)mean)[t];
    float4 vr = ((const float4*)var)[t];
    acc.x = (acc.x - mn.x) * rsqrtf(vr.x + 1e-5f) * g.x + be.x;
    acc.y = (acc.y - mn.y) * rsqrtf(vr.y + 1e-5f) * g.y + be.y;
    acc.z = (acc.z - mn.z) * rsqrtf(vr.z + 1e-5f) * g.z + be.z;
    acc.w = (acc.w - mn.w) * rsqrtf(vr.w + 1e-5f) * g.w + be.w;
    ((float4*)(ctx + (size_t)b * D2))[t] = acc;
}

// K3r: fused {kreduce for hidden (blocks 0..63)} + {p_gen (blocks 64..95)}
__global__ void k3r_pgen(const float* __restrict__ parts, float* __restrict__ out,
                         const float* __restrict__ bias,
                         const float* __restrict__ ctx, const float* __restrict__ h,
                         const float* __restrict__ c, const float* __restrict__ di,
                         const float* __restrict__ Wp, const float* __restrict__ bp,
                         float* __restrict__ pg){
    int t = threadIdx.x;
    if (blockIdx.x < 64){
        int i = blockIdx.x * 256 + t;              // n = B*D = 16384
        float s = 0.f;
        for (int p = 0; p < 16; ++p) s += parts[(size_t)p * (B * D) + i];
        s += bias[i & (D - 1)];
        out[i] = s;
        return;
    }
    int b = blockIdx.x - 64;
    float acc = 0.f;
    for (int k = t; k < D5; k += 256){
        float x;
        if (k < D2)            x = ctx[b * D2 + k];
        else if (k < D2 + D)   x = h[b * D + (k - D2)];
        else if (k < 2 * D2)   x = c[b * D + (k - D2 - D)];
        else                   x = di[b * D + (k - 2 * D2)];
        acc += x * Wp[k];
    }
    __shared__ float red[256];
    red[t] = acc; __syncthreads();
    for (int o = 128; o > 0; o >>= 1){
        if (t < o) red[t] += red[t + o];
        __syncthreads();
    }
    if (t == 0){
        float z = red[0] + bp[0];
        pg[b] = 1.0f / (1.0f + __expf(-z));
    }
}

// gemm_vocab64: lred[b][v] = hidden[b] . W_v2[v] + b_v2[v]; fused per-v-tile
// online-softmax stats. v-tile 64, 128 threads (2 waves), full K=512.
// 766 blocks -> ~3 blocks/CU (vs 383 blocks = 1.5/CU makespan imbalance).
__global__ __launch_bounds__(128) void gemm_vocab64(
    const float* __restrict__ W, const float* __restrict__ hid,
    const float* __restrict__ b2, float* __restrict__ lred,
    float* __restrict__ mch, float* __restrict__ sch)
{
    __shared__ float sW[16 * 68];
    __shared__ float sX[16 * 32];
    const int t    = threadIdx.x;
    const int lane = t & 63;
    const int wave = t >> 6;
    const int v0   = blockIdx.x * 64;

    const int sr   = t & 63;           // staged W row within tile
    const int sh   = (t >> 6) * 8;     // k-half: 0 or 8
    const int vrow = v0 + sr;
    const size_t wb = (size_t)((vrow < VO) ? vrow : (VO - 1)) * D + sh;

    const int xbi = t >> 2;            // b index 0..31
    const int xq  = (t & 3) * 4;       // k quarter within 16

    float acc[16];
    #pragma unroll
    for (int j = 0; j < 16; ++j) acc[j] = 0.f;

    float4 wreg[2];
    float  xreg[4];
    wreg[0] = *(const float4*)&W[wb];
    wreg[1] = *(const float4*)&W[wb + 4];
    #pragma unroll
    for (int e = 0; e < 4; ++e) xreg[e] = hid[xbi * D + xq + e];

    for (int tl = 0; tl < 32; ++tl){
        sW[(sh + 0) * 68 + sr] = wreg[0].x;
        sW[(sh + 1) * 68 + sr] = wreg[0].y;
        sW[(sh + 2) * 68 + sr] = wreg[0].z;
        sW[(sh + 3) * 68 + sr] = wreg[0].w;
        sW[(sh + 4) * 68 + sr] = wreg[1].x;
        sW[(sh + 5) * 68 + sr] = wreg[1].y;
        sW[(sh + 6) * 68 + sr] = wreg[1].z;
        sW[(sh + 7) * 68 + sr] = wreg[1].w;
        #pragma unroll
        for (int e = 0; e < 4; ++e) sX[(xq + e) * 32 + xbi] = xreg[e];
        __syncthreads();
        if (tl + 1 < 32){
            const int kn = (tl + 1) * 16;
            wreg[0] = *(const float4*)&W[wb + kn];
            wreg[1] = *(const float4*)&W[wb + kn + 4];
            #pragma unroll
            for (int e = 0; e < 4; ++e) xreg[e] = hid[xbi * D + kn + xq + e];
        }
        #pragma unroll
        for (int kk = 0; kk < 16; ++kk){
            const float  w  = sW[kk * 68 + lane];
            const float4 x0 = *(const float4*)&sX[kk * 32 + wave * 16 + 0];
            const float4 x1 = *(const float4*)&sX[kk * 32 + wave * 16 + 4];
            const float4 x2 = *(const float4*)&sX[kk * 32 + wave * 16 + 8];
            const float4 x3 = *(const float4*)&sX[kk * 32 + wave * 16 + 12];
            acc[0]  += w * x0.x; acc[1]  += w * x0.y; acc[2]  += w * x0.z; acc[3]  += w * x0.w;
            acc[4]  += w * x1.x; acc[5]  += w * x1.y; acc[6]  += w * x1.z; acc[7]  += w * x1.w;
            acc[8]  += w * x2.x; acc[9]  += w * x2.y; acc[10] += w * x2.z; acc[11] += w * x2.w;
            acc[12] += w * x3.x; acc[13] += w * x3.y; acc[14] += w * x3.z; acc[15] += w * x3.w;
        }
        __syncthreads();
    }

    // epilogue: +b_v2, write lred, per-b wave butterfly softmax stats
    const int  va    = v0 + lane;
    const bool valid = va < VO;
    const float b2v  = valid ? b2[va] : 0.f;

    #pragma unroll
    for (int j = 0; j < 16; ++j){
        const int b = wave * 16 + j;
        float l = acc[j] + b2v;
        if (valid) lred[(size_t)b * VO + va] = l;
        float m = valid ? l : -1e30f;
        #pragma unroll
        for (int off = 1; off < 64; off <<= 1) m = fmaxf(m, __shfl_xor(m, off, 64));
        float sv = valid ? __expf(l - m) : 0.f;
        #pragma unroll
        for (int off = 1; off < 64; off <<= 1) sv += __shfl_xor(sv, off, 64);
        if (lane == 0){
            mch[b * NCHV + blockIdx.x] = m;
            sch[b * NCHV + blockIdx.x] = sv;
        }
    }
}

// kC: combine chunk stats in-block (replaces kB), then
// pf[b][v] = pg[b]/S * exp(lred - M); chunk NCH zero-fills the OOV pad
__global__ void kC_final2(const float* __restrict__ lred, const float* __restrict__ mch,
                          const float* __restrict__ sch, const float* __restrict__ pg,
                          float* __restrict__ pf){
    int b = blockIdx.x, c = blockIdx.y, t = threadIdx.x;
    if (c == NCH){
        for (int v = VO + t; v < V; v += 256) pf[(size_t)b * V + v] = 0.f;
        return;
    }
    __shared__ float sm[256], ss[256];
    float m = -1e30f, s = 0.f;
    for (int ch = t; ch < NCHV; ch += 256){
        float mc = mch[b * NCHV + ch], sc = sch[b * NCHV + ch];
        float M = fmaxf(m, mc);
        s = s * __expf(m - M) + sc * __expf(mc - M);
        m = M;
    }
    sm[t] = m; ss[t] = s; __syncthreads();
    for (int o = 128; o > 0; o >>= 1){
        if (t < o){
            float m1 = sm[t], m2 = sm[t + o];
            float M = fmaxf(m1, m2);
            ss[t] = ss[t] * __expf(m1 - M) + ss[t + o] * __expf(m2 - M);
            sm[t] = M;
        }
        __syncthreads();
    }
    float M  = sm[0];
    float sc = pg[b] / ss[0];
    for (int v = c * CHW + t; v < (c + 1) * CHW; v += 256)
        pf[(size_t)b * V + v] = sc * __expf(lred[(size_t)b * VO + v] - M);
}

// K5b: scatter add (1-p_gen)*attn at src indices (32K atomics — negligible)
__global__ void k5b_scatter(const int* __restrict__ src, const float* __restrict__ attn,
                            const float* __restrict__ pg, float* __restrict__ pf){
    int b = blockIdx.x, t = threadIdx.x;
    float c1 = 1.0f - pg[b];
    for (int s = t; s < S; s += 256){
        int idx = src[b * S + s];
        atomicAdd(&pf[(size_t)b * V + idx], c1 * attn[b * S + s]);
    }
}

extern "C" void kernel_launch(void* const* d_in, const int* in_sizes, int n_in,
                              void* d_out, int out_size, void* d_ws, size_t ws_size,
                              hipStream_t stream){
    (void)in_sizes; (void)n_in; (void)out_size; (void)ws_size;
    const float* dec_output = (const float*)d_in[0];
    const float* h          = (const float*)d_in[1];
    const float* c          = (const float*)d_in[2];
    const float* dec_inp    = (const float*)d_in[3];
    const float* enc_op     = (const float*)d_in[4];
    const float* enc_op1    = (const float*)d_in[5];
    const int*   src        = (const int*)d_in[6];
    const float* W_dec      = (const float*)d_in[7];
    const float* b_dec      = (const float*)d_in[8];
    const float* w_attn     = (const float*)d_in[9];
    const float* W_v1       = (const float*)d_in[10];
    const float* b_v1       = (const float*)d_in[11];
    const float* W_v2       = (const float*)d_in[12];
    const float* b_v2       = (const float*)d_in[13];
    const float* W_p        = (const float*)d_in[14];
    const float* b_p        = (const float*)d_in[15];
    const float* bn_g       = (const float*)d_in[16];
    const float* bn_b       = (const float*)d_in[17];
    const float* bn_m       = (const float*)d_in[18];
    const float* bn_v       = (const float*)d_in[19];

    float* ws = (float*)d_ws;
    float* p1       = ws;                    // 16*32768   = 524288
    float* dec_op1  = ws + 524288;           // 32768
    float* p3       = ws + 557056;           // 16*16384   = 262144
    float* hidden   = ws + 819200;           // 16384
    float* lred     = ws + 835584;           // 1568000
    float* attn_lg  = ws + 2403584;          // 32768
    float* ctx_part = ws + 2436352;          // 1048576
    float* pg       = ws + 3484928;          // 32
    float* mch      = ws + 3484960;          // 32*766 = 24512
    float* sch      = ws + 3509472;          // 24512
    float* pm       = ws + 3533984;          // 32*64 = 2048
    float* ps       = ws + 3536032;          // 2048  (total ~14.2 MB)

    float* pf   = (float*)d_out;             // [32,50000]
    float* attn = pf + 1600000;              // [32,1024]
    float* ctx  = pf + 1632768;              // [32,1024]

    // k1: dec_op1 = [h;c] @ W_dec^T  (b_dec folded into k2a)
    gemm_nt <<<dim3(4, 16),  256, 0, stream>>>(W_dec, D2, D2, h, c, D, D, D, p1, 64);
    kreduce <<<128,          256, 0, stream>>>(p1, dec_op1, B * D2, 16, nullptr, 0);
    // k2a: logits + per-tile masked softmax partials (k2b folded into k2c)
    k2a_logit<<<dim3(B, 64), 256, 0, stream>>>(enc_op1, dec_op1, b_dec, w_attn, src,
                                               attn_lg, pm, ps);
    k2c_attn_ctx<<<dim3(B, 32), 256, 0, stream>>>(enc_op, attn_lg, src, pm, ps,
                                                  attn, ctx_part);
    k2d_ctxbn<<<B,           256, 0, stream>>>(ctx_part, bn_g, bn_b, bn_m, bn_v, ctx);
    // k3: hidden = [dec_output;ctx] @ W_v1^T + b_v1 (bias + pgen fused in k3r)
    gemm_nt <<<dim3(2, 16),  256, 0, stream>>>(W_v1, D, D + D2, dec_output, ctx,
                                               D, D, D2, p3, 96);
    k3r_pgen<<<96,           256, 0, stream>>>(p3, hidden, b_v1,
                                               ctx, h, c, dec_inp, W_p, b_p, pg);
    // k4: lred = hidden @ W_v2^T + b_v2, fused chunk softmax stats (766 blocks)
    gemm_vocab64<<<NCHV,     128, 0, stream>>>(W_v2, hidden, b_v2, lred, mch, sch);
    // kB folded into kC_final2
    kC_final2<<<dim3(B, NCH + 1), 256, 0, stream>>>(lred, mch, sch, pg, pf);
    k5b_scatter<<<B,         256, 0, stream>>>(src, attn, pg, pf);
}

// Round 2
// 475.437 us; speedup vs baseline: 1.0660x; 1.0660x over previous
//
#include <hip/hip_runtime.h>

#define B    32
#define S    1024
#define D    512
#define D2   1024
#define D5   2560
#define V    50000
#define VO   49000
#define NCH  14          // vocab chunks for kC finalize (14*3500 = 49000)
#define CHW  3500
#define NCHV 256         // gemm_vocab192 v-tiles (256*192 = 49152 >= 49000)
#define VT   192         // vocab v-tile

__device__ __forceinline__ float fast_tanh(float x){
    float e = __expf(2.0f * x);
    return 1.0f - __fdividef(2.0f, e + 1.0f);
}

// gemm_nt: parts[(ks*B + b)*Nreal + v] = sum_{k in slice ks} W[v][k] * X(b,k)
// X(b,k) = (k < xsplit ? xa[b*xstra+k] : xb[b*xstrb+k-xsplit])
// v-tile 256, 32 b, 16-k inner tiles, register-prefetch pipeline. No atomics.
__global__ __launch_bounds__(256) void gemm_nt(
    const float* __restrict__ W, int Nreal, int K,
    const float* __restrict__ xa, const float* __restrict__ xb,
    int xsplit, int xstra, int xstrb,
    float* __restrict__ parts, int KS)
{
    __shared__ float sW[16 * 260];
    __shared__ float sX[16 * 32];
    const int t    = threadIdx.x;
    const int lane = t & 63;
    const int v0   = blockIdx.x * 256;
    const int ks0  = blockIdx.y * KS;
    const int b0   = (t >> 6) * 8;

    const int vrow  = v0 + t;
    const size_t wb = (size_t)((vrow < Nreal) ? vrow : (Nreal - 1)) * K;

    float acc[4][8];
    #pragma unroll
    for (int i = 0; i < 4; ++i)
        #pragma unroll
        for (int j = 0; j < 8; ++j) acc[i][j] = 0.f;

    const int  xbi  = t >> 2;
    const int  xq   = t & 3;
    const bool xact = t < 128;

    float4 wreg[4];
    float  xreg[4];
    #pragma unroll
    for (int e = 0; e < 4; ++e) wreg[e] = *(const float4*)&W[wb + ks0 + e * 4];
    if (xact){
        #pragma unroll
        for (int e = 0; e < 4; ++e){
            int k = ks0 + xq * 4 + e;
            xreg[e] = (k < xsplit) ? xa[xbi * xstra + k] : xb[xbi * xstrb + (k - xsplit)];
        }
    }

    const int ntiles = KS >> 4;
    for (int tl = 0; tl < ntiles; ++tl){
        #pragma unroll
        for (int e = 0; e < 4; ++e){
            sW[(e * 4 + 0) * 260 + t] = wreg[e].x;
            sW[(e * 4 + 1) * 260 + t] = wreg[e].y;
            sW[(e * 4 + 2) * 260 + t] = wreg[e].z;
            sW[(e * 4 + 3) * 260 + t] = wreg[e].w;
        }
        if (xact){
            #pragma unroll
            for (int e = 0; e < 4; ++e) sX[(xq * 4 + e) * 32 + xbi] = xreg[e];
        }
        __syncthreads();
        if (tl + 1 < ntiles){
            int kn = ks0 + (tl + 1) * 16;
            #pragma unroll
            for (int e = 0; e < 4; ++e) wreg[e] = *(const float4*)&W[wb + kn + e * 4];
            if (xact){
                #pragma unroll
                for (int e = 0; e < 4; ++e){
                    int k = kn + xq * 4 + e;
                    xreg[e] = (k < xsplit) ? xa[xbi * xstra + k] : xb[xbi * xstrb + (k - xsplit)];
                }
            }
        }
        #pragma unroll
        for (int kk = 0; kk < 16; ++kk){
            const float4 w0 = *(const float4*)&sW[kk * 260 + lane * 4];
            const float4 x0 = *(const float4*)&sX[kk * 32 + b0];
            const float4 x1 = *(const float4*)&sX[kk * 32 + b0 + 4];
            const float wv[4] = {w0.x, w0.y, w0.z, w0.w};
            const float xv[8] = {x0.x, x0.y, x0.z, x0.w, x1.x, x1.y, x1.z, x1.w};
            #pragma unroll
            for (int i = 0; i < 4; ++i)
                #pragma unroll
                for (int j = 0; j < 8; ++j)
                    acc[i][j] += wv[i] * xv[j];
        }
        __syncthreads();
    }
    const int vbase = v0 + lane * 4;
    if (vbase < Nreal){
        const size_t pb = (size_t)blockIdx.y * B;
        #pragma unroll
        for (int j = 0; j < 8; ++j){
            float4 o = make_float4(acc[0][j], acc[1][j], acc[2][j], acc[3][j]);
            *(float4*)&parts[(pb + b0 + j) * (size_t)Nreal + vbase] = o;
        }
    }
}

// reduce parts over splits (+ optional per-row bias, row length = bmask+1 pow2)
__global__ void kreduce(const float* __restrict__ parts, float* __restrict__ out,
                        int n, int nsplit, const float* __restrict__ bias, int bmask){
    int i = blockIdx.x * 256 + threadIdx.x;
    if (i < n){
        float s = 0.f;
        for (int p = 0; p < nsplit; ++p) s += parts[(size_t)p * n + i];
        if (bias) s += bias[i & bmask];
        out[i] = s;
    }
}

// K2a: attn logit[b][s] = sum_d tanh(enc1[b][s][d] + dec_op1[b][d] + b_dec[d]) * w_attn[d]
// Also emits per-(b,tile) masked-softmax partials over its 16 rows:
//   pm = max(l) (unmasked), ps = sum mask * exp(l - pm)
__global__ void k2a_logit(const float* __restrict__ enc1, const float* __restrict__ dop1,
                          const float* __restrict__ bdec, const float* __restrict__ wat,
                          const int* __restrict__ src,
                          float* __restrict__ lg, float* __restrict__ pm,
                          float* __restrict__ ps){
    int b = blockIdx.x;
    int wave = threadIdx.x >> 6, lane = threadIdx.x & 63;
    int s0 = blockIdx.y * 16 + wave * 4;
    __shared__ float sd[D2], sw[D2];
    __shared__ float slog[16];
    for (int i = threadIdx.x; i < D2; i += 256){
        sd[i] = dop1[b * D2 + i] + bdec[i];
        sw[i] = wat[i];
    }
    __syncthreads();
    const float4* sd4 = (const float4*)sd;
    const float4* sw4 = (const float4*)sw;
    for (int r = 0; r < 4; ++r){
        int s = s0 + r;
        const float4* row = (const float4*)(enc1 + ((size_t)b * S + s) * D2);
        float acc = 0.f;
        #pragma unroll
        for (int i = 0; i < 4; ++i){
            int k4 = i * 64 + lane;
            float4 e = row[k4]; float4 dv = sd4[k4]; float4 wv = sw4[k4];
            acc += fast_tanh(e.x + dv.x) * wv.x + fast_tanh(e.y + dv.y) * wv.y
                 + fast_tanh(e.z + dv.z) * wv.z + fast_tanh(e.w + dv.w) * wv.w;
        }
        #pragma unroll
        for (int off = 32; off > 0; off >>= 1) acc += __shfl_down(acc, off, 64);
        if (lane == 0){
            lg[b * S + s] = acc;
            slog[wave * 4 + r] = acc;
        }
    }
    __syncthreads();
    if (threadIdx.x == 0){
        int sbase = blockIdx.y * 16;
        float m = -1e30f;
        #pragma unroll
        for (int i = 0; i < 16; ++i) m = fmaxf(m, slog[i]);
        float sum = 0.f;
        #pragma unroll
        for (int i = 0; i < 16; ++i){
            bool keep = src[b * S + sbase + i] != 0;
            sum += keep ? __expf(slog[i] - m) : 0.f;
        }
        pm[b * 64 + blockIdx.y] = m;
        ps[b * 64 + blockIdx.y] = sum;
    }
}

// K2c: combine 64 tile stats -> masked softmax attn (output 1) for this block's
// 32 s values, then context partials over s-splits.
__global__ void k2c_attn_ctx(const float* __restrict__ enc, const float* __restrict__ lg,
                             const int* __restrict__ src, const float* __restrict__ pm,
                             const float* __restrict__ ps,
                             float* __restrict__ attn, float* __restrict__ part){
    int b = blockIdx.x, sp = blockIdx.y, t = threadIdx.x;
    __shared__ float sa[32];
    __shared__ float sMS[2];
    if (t < 64){
        float m = pm[b * 64 + t];
        float s = ps[b * 64 + t];
        float M = m;
        #pragma unroll
        for (int off = 1; off < 64; off <<= 1) M = fmaxf(M, __shfl_xor(M, off, 64));
        float sv = s * __expf(m - M);
        #pragma unroll
        for (int off = 1; off < 64; off <<= 1) sv += __shfl_xor(sv, off, 64);
        if (t == 0){ sMS[0] = M; sMS[1] = sv; }
    }
    __syncthreads();
    float M   = sMS[0];
    float inv = 1.0f / sMS[1];
    if (t < 32){
        int s = sp * 32 + t;
        float l = lg[b * S + s];
        bool keep = src[b * S + s] != 0;
        float a = keep ? __expf(l - M) * inv : 0.f;
        attn[b * S + s] = a;
        sa[t] = a;
    }
    __syncthreads();
    const float4* base = (const float4*)(enc + ((size_t)b * S + sp * 32) * D2);
    float4 acc = make_float4(0.f, 0.f, 0.f, 0.f);
    #pragma unroll 4
    for (int s = 0; s < 32; ++s){
        float a = sa[s];
        float4 e = base[s * (D2 / 4) + t];
        acc.x += a * e.x; acc.y += a * e.y; acc.z += a * e.z; acc.w += a * e.w;
    }
    ((float4*)(part + ((size_t)(b * 32 + sp)) * D2))[t] = acc;
}

// K2d: reduce partials + batchnorm -> context (output 2)
__global__ void k2d_ctxbn(const float* __restrict__ part, const float* __restrict__ gamma,
                          const float* __restrict__ beta, const float* __restrict__ mean,
                          const float* __restrict__ var, float* __restrict__ ctx){
    int b = blockIdx.x, t = threadIdx.x;
    float4 acc = make_float4(0.f, 0.f, 0.f, 0.f);
    for (int sp = 0; sp < 32; ++sp){
        float4 p = ((const float4*)(part + ((size_t)(b * 32 + sp)) * D2))[t];
        acc.x += p.x; acc.y += p.y; acc.z += p.z; acc.w += p.w;
    }
    float4 g  = ((const float4*)gamma)[t];
    float4 be = ((const float4*)beta)[t];
    float4 mn = ((const float4*)mean)[t];
    float4 vr = ((const float4*)var)[t];
    acc.x = (acc.x - mn.x) * rsqrtf(vr.x + 1e-5f) * g.x + be.x;
    acc.y = (acc.y - mn.y) * rsqrtf(vr.y + 1e-5f) * g.y + be.y;
    acc.z = (acc.z - mn.z) * rsqrtf(vr.z + 1e-5f) * g.z + be.z;
    acc.w = (acc.w - mn.w) * rsqrtf(vr.w + 1e-5f) * g.w + be.w;
    ((float4*)(ctx + (size_t)b * D2))[t] = acc;
}

// K3r: fused {kreduce for hidden (blocks 0..63)} + {p_gen (blocks 64..95)}
__global__ void k3r_pgen(const float* __restrict__ parts, float* __restrict__ out,
                         const float* __restrict__ bias,
                         const float* __restrict__ ctx, const float* __restrict__ h,
                         const float* __restrict__ c, const float* __restrict__ di,
                         const float* __restrict__ Wp, const float* __restrict__ bp,
                         float* __restrict__ pg){
    int t = threadIdx.x;
    if (blockIdx.x < 64){
        int i = blockIdx.x * 256 + t;              // n = B*D = 16384
        float s = 0.f;
        for (int p = 0; p < 16; ++p) s += parts[(size_t)p * (B * D) + i];
        s += bias[i & (D - 1)];
        out[i] = s;
        return;
    }
    int b = blockIdx.x - 64;
    float acc = 0.f;
    for (int k = t; k < D5; k += 256){
        float x;
        if (k < D2)            x = ctx[b * D2 + k];
        else if (k < D2 + D)   x = h[b * D + (k - D2)];
        else if (k < 2 * D2)   x = c[b * D + (k - D2 - D)];
        else                   x = di[b * D + (k - 2 * D2)];
        acc += x * Wp[k];
    }
    __shared__ float red[256];
    red[t] = acc; __syncthreads();
    for (int o = 128; o > 0; o >>= 1){
        if (t < o) red[t] += red[t + o];
        __syncthreads();
    }
    if (t == 0){
        float z = red[0] + bp[0];
        pg[b] = 1.0f / (1.0f + __expf(-z));
    }
}

// gemm_vocab192: lred[b][v] = hidden[b] . W_v2[v] + b_v2[v], fused per-v-tile
// online-softmax stats. v-tile 192, 256 blocks (1/CU, balanced), 256 threads.
// Per-thread 3v x 8b acc: 24 FMA per {3x b32 W + 2x b128 X-broadcast} -> VALU-
// dominant. Staging: 192 threads write W rows stride-1 (conflict-free); 64
// threads write X with bank = lane&31 (conflict-free).
__global__ __launch_bounds__(256) void gemm_vocab192(
    const float* __restrict__ W, const float* __restrict__ hid,
    const float* __restrict__ b2, float* __restrict__ lred,
    float* __restrict__ mch, float* __restrict__ sch)
{
    __shared__ float sW[16 * VT];      // [k][v]  12 KB
    __shared__ float sX[16 * 32];      // [k][b]   2 KB
    const int t    = threadIdx.x;
    const int lane = t & 63;
    const int wave = t >> 6;
    const int v0   = blockIdx.x * VT;
    const int b0   = wave * 8;

    float acc[3][8];
    #pragma unroll
    for (int i = 0; i < 3; ++i)
        #pragma unroll
        for (int j = 0; j < 8; ++j) acc[i][j] = 0.f;

    // staging roles
    const bool wstage = t < VT;
    const int  wr     = t;                          // W row within tile (if wstage)
    const int  vr     = v0 + wr;
    const size_t wb   = (size_t)((vr < VO) ? vr : (VO - 1)) * D;
    const int  u      = t - VT;                     // X stager index 0..63
    const int  xb     = u & 31;
    const int  xk     = (u >> 5) * 8;               // 0 or 8

    float4 wreg[4];
    float  xreg[8];
    if (wstage){
        #pragma unroll
        for (int e = 0; e < 4; ++e) wreg[e] = *(const float4*)&W[wb + e * 4];
    } else {
        #pragma unroll
        for (int e = 0; e < 8; ++e) xreg[e] = hid[xb * D + xk + e];
    }

    for (int tl = 0; tl < 32; ++tl){
        if (wstage){
            #pragma unroll
            for (int e = 0; e < 4; ++e){
                sW[(e * 4 + 0) * VT + wr] = wreg[e].x;
                sW[(e * 4 + 1) * VT + wr] = wreg[e].y;
                sW[(e * 4 + 2) * VT + wr] = wreg[e].z;
                sW[(e * 4 + 3) * VT + wr] = wreg[e].w;
            }
        } else {
            #pragma unroll
            for (int e = 0; e < 8; ++e) sX[(xk + e) * 32 + xb] = xreg[e];
        }
        __syncthreads();
        if (tl + 1 < 32){
            const int kn = (tl + 1) * 16;
            if (wstage){
                #pragma unroll
                for (int e = 0; e < 4; ++e) wreg[e] = *(const float4*)&W[wb + kn + e * 4];
            } else {
                #pragma unroll
                for (int e = 0; e < 8; ++e) xreg[e] = hid[xb * D + kn + xk + e];
            }
        }
        #pragma unroll
        for (int kk = 0; kk < 16; ++kk){
            const float w0 = sW[kk * VT + lane];
            const float w1 = sW[kk * VT + 64 + lane];
            const float w2 = sW[kk * VT + 128 + lane];
            const float4 x0 = *(const float4*)&sX[kk * 32 + b0];
            const float4 x1 = *(const float4*)&sX[kk * 32 + b0 + 4];
            const float xv[8] = {x0.x, x0.y, x0.z, x0.w, x1.x, x1.y, x1.z, x1.w};
            #pragma unroll
            for (int j = 0; j < 8; ++j){
                acc[0][j] += w0 * xv[j];
                acc[1][j] += w1 * xv[j];
                acc[2][j] += w2 * xv[j];
            }
        }
        __syncthreads();
    }

    // epilogue: +b_v2, write lred, per-b 64-lane butterfly softmax stats
    bool  valid[3];
    float bias[3];
    #pragma unroll
    for (int i = 0; i < 3; ++i){
        int v = v0 + i * 64 + lane;
        valid[i] = v < VO;
        bias[i]  = valid[i] ? b2[v] : 0.f;
    }
    #pragma unroll
    for (int j = 0; j < 8; ++j){
        const int b = b0 + j;
        float l[3];
        float m = -1e30f;
        #pragma unroll
        for (int i = 0; i < 3; ++i){
            l[i] = acc[i][j] + bias[i];
            if (valid[i]){
                lred[(size_t)b * VO + v0 + i * 64 + lane] = l[i];
                m = fmaxf(m, l[i]);
            }
        }
        float s = 0.f;
        #pragma unroll
        for (int i = 0; i < 3; ++i)
            s += valid[i] ? __expf(l[i] - m) : 0.f;
        #pragma unroll
        for (int off = 1; off < 64; off <<= 1){
            float m2 = __shfl_xor(m, off, 64);
            float s2 = __shfl_xor(s, off, 64);
            float M  = fmaxf(m, m2);
            s = s * __expf(m - M) + s2 * __expf(m2 - M);
            m = M;
        }
        if (lane == 0){
            mch[b * NCHV + blockIdx.x] = m;
            sch[b * NCHV + blockIdx.x] = s;
        }
    }
}

// kC: combine chunk stats in-block, then pf[b][v] = pg[b]/S * exp(lred - M);
// chunk NCH zero-fills the OOV pad
__global__ void kC_final2(const float* __restrict__ lred, const float* __restrict__ mch,
                          const float* __restrict__ sch, const float* __restrict__ pg,
                          float* __restrict__ pf){
    int b = blockIdx.x, c = blockIdx.y, t = threadIdx.x;
    if (c == NCH){
        for (int v = VO + t; v < V; v += 256) pf[(size_t)b * V + v] = 0.f;
        return;
    }
    __shared__ float sm[256], ss[256];
    float m = -1e30f, s = 0.f;
    for (int ch = t; ch < NCHV; ch += 256){
        float mc = mch[b * NCHV + ch], sc = sch[b * NCHV + ch];
        float M = fmaxf(m, mc);
        s = s * __expf(m - M) + sc * __expf(mc - M);
        m = M;
    }
    sm[t] = m; ss[t] = s; __syncthreads();
    for (int o = 128; o > 0; o >>= 1){
        if (t < o){
            float m1 = sm[t], m2 = sm[t + o];
            float M = fmaxf(m1, m2);
            ss[t] = ss[t] * __expf(m1 - M) + ss[t + o] * __expf(m2 - M);
            sm[t] = M;
        }
        __syncthreads();
    }
    float M  = sm[0];
    float sc = pg[b] / ss[0];
    for (int v = c * CHW + t; v < (c + 1) * CHW; v += 256)
        pf[(size_t)b * V + v] = sc * __expf(lred[(size_t)b * VO + v] - M);
}

// K5b: scatter add (1-p_gen)*attn at src indices (32K atomics — negligible)
__global__ void k5b_scatter(const int* __restrict__ src, const float* __restrict__ attn,
                            const float* __restrict__ pg, float* __restrict__ pf){
    int b = blockIdx.x, t = threadIdx.x;
    float c1 = 1.0f - pg[b];
    for (int s = t; s < S; s += 256){
        int idx = src[b * S + s];
        atomicAdd(&pf[(size_t)b * V + idx], c1 * attn[b * S + s]);
    }
}

extern "C" void kernel_launch(void* const* d_in, const int* in_sizes, int n_in,
                              void* d_out, int out_size, void* d_ws, size_t ws_size,
                              hipStream_t stream){
    (void)in_sizes; (void)n_in; (void)out_size; (void)ws_size;
    const float* dec_output = (const float*)d_in[0];
    const float* h          = (const float*)d_in[1];
    const float* c          = (const float*)d_in[2];
    const float* dec_inp    = (const float*)d_in[3];
    const float* enc_op     = (const float*)d_in[4];
    const float* enc_op1    = (const float*)d_in[5];
    const int*   src        = (const int*)d_in[6];
    const float* W_dec      = (const float*)d_in[7];
    const float* b_dec      = (const float*)d_in[8];
    const float* w_attn     = (const float*)d_in[9];
    const float* W_v1       = (const float*)d_in[10];
    const float* b_v1       = (const float*)d_in[11];
    const float* W_v2       = (const float*)d_in[12];
    const float* b_v2       = (const float*)d_in[13];
    const float* W_p        = (const float*)d_in[14];
    const float* b_p        = (const float*)d_in[15];
    const float* bn_g       = (const float*)d_in[16];
    const float* bn_b       = (const float*)d_in[17];
    const float* bn_m       = (const float*)d_in[18];
    const float* bn_v       = (const float*)d_in[19];

    float* ws = (float*)d_ws;
    float* p1       = ws;                    // 16*32768   = 524288
    float* dec_op1  = ws + 524288;           // 32768
    float* p3       = ws + 557056;           // 16*16384   = 262144
    float* hidden   = ws + 819200;           // 16384
    float* lred     = ws + 835584;           // 1568000
    float* attn_lg  = ws + 2403584;          // 32768
    float* ctx_part = ws + 2436352;          // 1048576
    float* pg       = ws + 3484928;          // 32
    float* mch      = ws + 3484960;          // 32*256 = 8192
    float* sch      = ws + 3493152;          // 8192
    float* pm       = ws + 3501344;          // 32*64 = 2048
    float* ps       = ws + 3503392;          // 2048  (total ~14 MB)

    float* pf   = (float*)d_out;             // [32,50000]
    float* attn = pf + 1600000;              // [32,1024]
    float* ctx  = pf + 1632768;              // [32,1024]

    // k1: dec_op1 = [h;c] @ W_dec^T  (b_dec folded into k2a)
    gemm_nt <<<dim3(4, 16),  256, 0, stream>>>(W_dec, D2, D2, h, c, D, D, D, p1, 64);
    kreduce <<<128,          256, 0, stream>>>(p1, dec_op1, B * D2, 16, nullptr, 0);
    // k2a: logits + per-tile masked softmax partials (k2b folded into k2c)
    k2a_logit<<<dim3(B, 64), 256, 0, stream>>>(enc_op1, dec_op1, b_dec, w_attn, src,
                                               attn_lg, pm, ps);
    k2c_attn_ctx<<<dim3(B, 32), 256, 0, stream>>>(enc_op, attn_lg, src, pm, ps,
                                                  attn, ctx_part);
    k2d_ctxbn<<<B,           256, 0, stream>>>(ctx_part, bn_g, bn_b, bn_m, bn_v, ctx);
    // k3: hidden = [dec_output;ctx] @ W_v1^T + b_v1 (bias + pgen fused in k3r)
    gemm_nt <<<dim3(2, 16),  256, 0, stream>>>(W_v1, D, D + D2, dec_output, ctx,
                                               D, D, D2, p3, 96);
    k3r_pgen<<<96,           256, 0, stream>>>(p3, hidden, b_v1,
                                               ctx, h, c, dec_inp, W_p, b_p, pg);
    // k4: lred = hidden @ W_v2^T + b_v2, fused chunk softmax stats (256 blocks)
    gemm_vocab192<<<NCHV,    256, 0, stream>>>(W_v2, hidden, b_v2, lred, mch, sch);
    kC_final2<<<dim3(B, NCH + 1), 256, 0, stream>>>(lred, mch, sch, pg, pf);
    k5b_scatter<<<B,         256, 0, stream>>>(src, attn, pg, pf);
}

// Round 3
// 450.519 us; speedup vs baseline: 1.1250x; 1.0553x over previous
//
#include <hip/hip_runtime.h>

#define B    32
#define S    1024
#define D    512
#define D2   1024
#define D5   2560
#define V    50000
#define VO   49000
#define NCH  14          // vocab chunks for kC finalize (14*3500 = 49000)
#define CHW  3500
#define NCHV 256         // gemm_vocab192 v-tiles (256*192 = 49152 >= 49000)
#define VT   192         // vocab v-tile
#define K1SP 32          // k1 k-splits (KS=32)
#define K3SP 96          // k3 k-splits (KS=16)

__device__ __forceinline__ float fast_tanh(float x){
    float e = __expf(2.0f * x);
    return 1.0f - __fdividef(2.0f, e + 1.0f);
}

// gemm_nt: parts[(ks*B + b)*Nreal + v] = sum_{k in slice ks} W[v][k] * X(b,k)
// X(b,k) = (k < xsplit ? xa[b*xstra+k] : xb[b*xstrb+k-xsplit])
// v-tile 256, 32 b, 16-k inner tiles, register-prefetch pipeline. No atomics.
__global__ __launch_bounds__(256) void gemm_nt(
    const float* __restrict__ W, int Nreal, int K,
    const float* __restrict__ xa, const float* __restrict__ xb,
    int xsplit, int xstra, int xstrb,
    float* __restrict__ parts, int KS)
{
    __shared__ float sW[16 * 260];
    __shared__ float sX[16 * 32];
    const int t    = threadIdx.x;
    const int lane = t & 63;
    const int v0   = blockIdx.x * 256;
    const int ks0  = blockIdx.y * KS;
    const int b0   = (t >> 6) * 8;

    const int vrow  = v0 + t;
    const size_t wb = (size_t)((vrow < Nreal) ? vrow : (Nreal - 1)) * K;

    float acc[4][8];
    #pragma unroll
    for (int i = 0; i < 4; ++i)
        #pragma unroll
        for (int j = 0; j < 8; ++j) acc[i][j] = 0.f;

    const int  xbi  = t >> 2;
    const int  xq   = t & 3;
    const bool xact = t < 128;

    float4 wreg[4];
    float  xreg[4];
    #pragma unroll
    for (int e = 0; e < 4; ++e) wreg[e] = *(const float4*)&W[wb + ks0 + e * 4];
    if (xact){
        #pragma unroll
        for (int e = 0; e < 4; ++e){
            int k = ks0 + xq * 4 + e;
            xreg[e] = (k < xsplit) ? xa[xbi * xstra + k] : xb[xbi * xstrb + (k - xsplit)];
        }
    }

    const int ntiles = KS >> 4;
    for (int tl = 0; tl < ntiles; ++tl){
        #pragma unroll
        for (int e = 0; e < 4; ++e){
            sW[(e * 4 + 0) * 260 + t] = wreg[e].x;
            sW[(e * 4 + 1) * 260 + t] = wreg[e].y;
            sW[(e * 4 + 2) * 260 + t] = wreg[e].z;
            sW[(e * 4 + 3) * 260 + t] = wreg[e].w;
        }
        if (xact){
            #pragma unroll
            for (int e = 0; e < 4; ++e) sX[(xq * 4 + e) * 32 + xbi] = xreg[e];
        }
        __syncthreads();
        if (tl + 1 < ntiles){
            int kn = ks0 + (tl + 1) * 16;
            #pragma unroll
            for (int e = 0; e < 4; ++e) wreg[e] = *(const float4*)&W[wb + kn + e * 4];
            if (xact){
                #pragma unroll
                for (int e = 0; e < 4; ++e){
                    int k = kn + xq * 4 + e;
                    xreg[e] = (k < xsplit) ? xa[xbi * xstra + k] : xb[xbi * xstrb + (k - xsplit)];
                }
            }
        }
        #pragma unroll
        for (int kk = 0; kk < 16; ++kk){
            const float4 w0 = *(const float4*)&sW[kk * 260 + lane * 4];
            const float4 x0 = *(const float4*)&sX[kk * 32 + b0];
            const float4 x1 = *(const float4*)&sX[kk * 32 + b0 + 4];
            const float wv[4] = {w0.x, w0.y, w0.z, w0.w};
            const float xv[8] = {x0.x, x0.y, x0.z, x0.w, x1.x, x1.y, x1.z, x1.w};
            #pragma unroll
            for (int i = 0; i < 4; ++i)
                #pragma unroll
                for (int j = 0; j < 8; ++j)
                    acc[i][j] += wv[i] * xv[j];
        }
        __syncthreads();
    }
    const int vbase = v0 + lane * 4;
    if (vbase < Nreal){
        const size_t pb = (size_t)blockIdx.y * B;
        #pragma unroll
        for (int j = 0; j < 8; ++j){
            float4 o = make_float4(acc[0][j], acc[1][j], acc[2][j], acc[3][j]);
            *(float4*)&parts[(pb + b0 + j) * (size_t)Nreal + vbase] = o;
        }
    }
}

// reduce parts over splits (+ optional per-row bias, row length = bmask+1 pow2)
__global__ void kreduce(const float* __restrict__ parts, float* __restrict__ out,
                        int n, int nsplit, const float* __restrict__ bias, int bmask){
    int i = blockIdx.x * 256 + threadIdx.x;
    if (i < n){
        float s = 0.f;
        for (int p = 0; p < nsplit; ++p) s += parts[(size_t)p * n + i];
        if (bias) s += bias[i & bmask];
        out[i] = s;
    }
}

// K2a: attn logit[b][s] = sum_d tanh(enc1[b][s][d] + dec_op1[b][d] + b_dec[d]) * w_attn[d]
// Register-resident dv/wv (no LDS round-trip), 2-deep row pipeline (prefetch
// next row's 4x float4 during compute), interleaved butterfly reduces.
// Also emits per-(b,tile) masked-softmax partials over its 16 rows.
__global__ void k2a_logit(const float* __restrict__ enc1, const float* __restrict__ dop1,
                          const float* __restrict__ bdec, const float* __restrict__ wat,
                          const int* __restrict__ src,
                          float* __restrict__ lg, float* __restrict__ pm,
                          float* __restrict__ ps){
    const int b    = blockIdx.x;
    const int wave = threadIdx.x >> 6, lane = threadIdx.x & 63;
    const int s0   = blockIdx.y * 16 + wave * 4;
    __shared__ float slog[16];

    // per-wave register copies of dec_op1[b]+b_dec and w_attn (L1-hot, tiny)
    const float4* dop4 = (const float4*)dop1 + b * 256;
    const float4* bd4  = (const float4*)bdec;
    const float4* wt4  = (const float4*)wat;
    float4 dv[4], wv[4];
    #pragma unroll
    for (int i = 0; i < 4; ++i){
        const int k4 = i * 64 + lane;
        float4 dd = dop4[k4], bb = bd4[k4];
        dv[i] = make_float4(dd.x + bb.x, dd.y + bb.y, dd.z + bb.z, dd.w + bb.w);
        wv[i] = wt4[k4];
    }

    const float4* row = (const float4*)(enc1 + ((size_t)b * S + s0) * D2);
    float4 cur[4], nxt[4];
    #pragma unroll
    for (int i = 0; i < 4; ++i) cur[i] = row[i * 64 + lane];

    float accs[4];
    #pragma unroll
    for (int r = 0; r < 4; ++r){
        if (r < 3){
            #pragma unroll
            for (int i = 0; i < 4; ++i) nxt[i] = row[(r + 1) * 256 + i * 64 + lane];
        }
        float a = 0.f;
        #pragma unroll
        for (int i = 0; i < 4; ++i){
            const float4 e = cur[i], d = dv[i], w = wv[i];
            a += fast_tanh(e.x + d.x) * w.x + fast_tanh(e.y + d.y) * w.y
               + fast_tanh(e.z + d.z) * w.z + fast_tanh(e.w + d.w) * w.w;
        }
        accs[r] = a;
        #pragma unroll
        for (int i = 0; i < 4; ++i) cur[i] = nxt[i];
    }
    #pragma unroll
    for (int off = 32; off > 0; off >>= 1){
        #pragma unroll
        for (int r = 0; r < 4; ++r) accs[r] += __shfl_down(accs[r], off, 64);
    }
    if (lane == 0){
        #pragma unroll
        for (int r = 0; r < 4; ++r){
            lg[b * S + s0 + r] = accs[r];
            slog[wave * 4 + r] = accs[r];
        }
    }
    __syncthreads();
    if (threadIdx.x == 0){
        int sbase = blockIdx.y * 16;
        float m = -1e30f;
        #pragma unroll
        for (int i = 0; i < 16; ++i) m = fmaxf(m, slog[i]);
        float sum = 0.f;
        #pragma unroll
        for (int i = 0; i < 16; ++i){
            bool keep = src[b * S + sbase + i] != 0;
            sum += keep ? __expf(slog[i] - m) : 0.f;
        }
        pm[b * 64 + blockIdx.y] = m;
        ps[b * 64 + blockIdx.y] = sum;
    }
}

// K2c: combine 64 tile stats -> masked softmax attn (output 1) for this block's
// 32 s values, then context partials. Dual accumulator chains + unroll for MLP.
__global__ void k2c_attn_ctx(const float* __restrict__ enc, const float* __restrict__ lg,
                             const int* __restrict__ src, const float* __restrict__ pm,
                             const float* __restrict__ ps,
                             float* __restrict__ attn, float* __restrict__ part){
    int b = blockIdx.x, sp = blockIdx.y, t = threadIdx.x;
    __shared__ float sa[32];
    __shared__ float sMS[2];
    if (t < 64){
        float m = pm[b * 64 + t];
        float s = ps[b * 64 + t];
        float M = m;
        #pragma unroll
        for (int off = 1; off < 64; off <<= 1) M = fmaxf(M, __shfl_xor(M, off, 64));
        float sv = s * __expf(m - M);
        #pragma unroll
        for (int off = 1; off < 64; off <<= 1) sv += __shfl_xor(sv, off, 64);
        if (t == 0){ sMS[0] = M; sMS[1] = sv; }
    }
    __syncthreads();
    float M   = sMS[0];
    float inv = 1.0f / sMS[1];
    if (t < 32){
        int s = sp * 32 + t;
        float l = lg[b * S + s];
        bool keep = src[b * S + s] != 0;
        float a = keep ? __expf(l - M) * inv : 0.f;
        attn[b * S + s] = a;
        sa[t] = a;
    }
    __syncthreads();
    const float4* base = (const float4*)(enc + ((size_t)b * S + sp * 32) * D2);
    float4 acc0 = make_float4(0.f, 0.f, 0.f, 0.f);
    float4 acc1 = make_float4(0.f, 0.f, 0.f, 0.f);
    #pragma unroll 4
    for (int s = 0; s < 32; s += 2){
        float a0 = sa[s], a1 = sa[s + 1];
        float4 e0 = base[s * 256 + t];
        float4 e1 = base[(s + 1) * 256 + t];
        acc0.x += a0 * e0.x; acc0.y += a0 * e0.y; acc0.z += a0 * e0.z; acc0.w += a0 * e0.w;
        acc1.x += a1 * e1.x; acc1.y += a1 * e1.y; acc1.z += a1 * e1.z; acc1.w += a1 * e1.w;
    }
    float4 acc = make_float4(acc0.x + acc1.x, acc0.y + acc1.y,
                             acc0.z + acc1.z, acc0.w + acc1.w);
    ((float4*)(part + ((size_t)(b * 32 + sp)) * D2))[t] = acc;
}

// K2d: reduce partials + batchnorm -> context (output 2)
__global__ void k2d_ctxbn(const float* __restrict__ part, const float* __restrict__ gamma,
                          const float* __restrict__ beta, const float* __restrict__ mean,
                          const float* __restrict__ var, float* __restrict__ ctx){
    int b = blockIdx.x, t = threadIdx.x;
    float4 acc = make_float4(0.f, 0.f, 0.f, 0.f);
    for (int sp = 0; sp < 32; ++sp){
        float4 p = ((const float4*)(part + ((size_t)(b * 32 + sp)) * D2))[t];
        acc.x += p.x; acc.y += p.y; acc.z += p.z; acc.w += p.w;
    }
    float4 g  = ((const float4*)gamma)[t];
    float4 be = ((const float4*)beta)[t];
    float4 mn = ((const float4*)mean)[t];
    float4 vr = ((const float4*)var)[t];
    acc.x = (acc.x - mn.x) * rsqrtf(vr.x + 1e-5f) * g.x + be.x;
    acc.y = (acc.y - mn.y) * rsqrtf(vr.y + 1e-5f) * g.y + be.y;
    acc.z = (acc.z - mn.z) * rsqrtf(vr.z + 1e-5f) * g.z + be.z;
    acc.w = (acc.w - mn.w) * rsqrtf(vr.w + 1e-5f) * g.w + be.w;
    ((float4*)(ctx + (size_t)b * D2))[t] = acc;
}

// K3r: fused {kreduce for hidden (blocks 0..63)} + {p_gen (blocks 64..95)}
__global__ void k3r_pgen(const float* __restrict__ parts, float* __restrict__ out,
                         const float* __restrict__ bias,
                         const float* __restrict__ ctx, const float* __restrict__ h,
                         const float* __restrict__ c, const float* __restrict__ di,
                         const float* __restrict__ Wp, const float* __restrict__ bp,
                         float* __restrict__ pg){
    int t = threadIdx.x;
    if (blockIdx.x < 64){
        int i = blockIdx.x * 256 + t;              // n = B*D = 16384
        float s = 0.f;
        for (int p = 0; p < K3SP; ++p) s += parts[(size_t)p * (B * D) + i];
        s += bias[i & (D - 1)];
        out[i] = s;
        return;
    }
    int b = blockIdx.x - 64;
    float acc = 0.f;
    for (int k = t; k < D5; k += 256){
        float x;
        if (k < D2)            x = ctx[b * D2 + k];
        else if (k < D2 + D)   x = h[b * D + (k - D2)];
        else if (k < 2 * D2)   x = c[b * D + (k - D2 - D)];
        else                   x = di[b * D + (k - 2 * D2)];
        acc += x * Wp[k];
    }
    __shared__ float red[256];
    red[t] = acc; __syncthreads();
    for (int o = 128; o > 0; o >>= 1){
        if (t < o) red[t] += red[t + o];
        __syncthreads();
    }
    if (t == 0){
        float z = red[0] + bp[0];
        pg[b] = 1.0f / (1.0f + __expf(-z));
    }
}

// gemm_vocab192: lred[b][v] = hidden[b] . W_v2[v] + b_v2[v], fused per-v-tile
// online-softmax stats. v-tile 192, 256 blocks (1/CU, balanced), 256 threads.
__global__ __launch_bounds__(256) void gemm_vocab192(
    const float* __restrict__ W, const float* __restrict__ hid,
    const float* __restrict__ b2, float* __restrict__ lred,
    float* __restrict__ mch, float* __restrict__ sch)
{
    __shared__ float sW[16 * VT];      // [k][v]  12 KB
    __shared__ float sX[16 * 32];      // [k][b]   2 KB
    const int t    = threadIdx.x;
    const int lane = t & 63;
    const int wave = t >> 6;
    const int v0   = blockIdx.x * VT;
    const int b0   = wave * 8;

    float acc[3][8];
    #pragma unroll
    for (int i = 0; i < 3; ++i)
        #pragma unroll
        for (int j = 0; j < 8; ++j) acc[i][j] = 0.f;

    const bool wstage = t < VT;
    const int  wr     = t;
    const int  vr     = v0 + wr;
    const size_t wb   = (size_t)((vr < VO) ? vr : (VO - 1)) * D;
    const int  u      = t - VT;
    const int  xb     = u & 31;
    const int  xk     = (u >> 5) * 8;

    float4 wreg[4];
    float  xreg[8];
    if (wstage){
        #pragma unroll
        for (int e = 0; e < 4; ++e) wreg[e] = *(const float4*)&W[wb + e * 4];
    } else {
        #pragma unroll
        for (int e = 0; e < 8; ++e) xreg[e] = hid[xb * D + xk + e];
    }

    for (int tl = 0; tl < 32; ++tl){
        if (wstage){
            #pragma unroll
            for (int e = 0; e < 4; ++e){
                sW[(e * 4 + 0) * VT + wr] = wreg[e].x;
                sW[(e * 4 + 1) * VT + wr] = wreg[e].y;
                sW[(e * 4 + 2) * VT + wr] = wreg[e].z;
                sW[(e * 4 + 3) * VT + wr] = wreg[e].w;
            }
        } else {
            #pragma unroll
            for (int e = 0; e < 8; ++e) sX[(xk + e) * 32 + xb] = xreg[e];
        }
        __syncthreads();
        if (tl + 1 < 32){
            const int kn = (tl + 1) * 16;
            if (wstage){
                #pragma unroll
                for (int e = 0; e < 4; ++e) wreg[e] = *(const float4*)&W[wb + kn + e * 4];
            } else {
                #pragma unroll
                for (int e = 0; e < 8; ++e) xreg[e] = hid[xb * D + kn + xk + e];
            }
        }
        #pragma unroll
        for (int kk = 0; kk < 16; ++kk){
            const float w0 = sW[kk * VT + lane];
            const float w1 = sW[kk * VT + 64 + lane];
            const float w2 = sW[kk * VT + 128 + lane];
            const float4 x0 = *(const float4*)&sX[kk * 32 + b0];
            const float4 x1 = *(const float4*)&sX[kk * 32 + b0 + 4];
            const float xv[8] = {x0.x, x0.y, x0.z, x0.w, x1.x, x1.y, x1.z, x1.w};
            #pragma unroll
            for (int j = 0; j < 8; ++j){
                acc[0][j] += w0 * xv[j];
                acc[1][j] += w1 * xv[j];
                acc[2][j] += w2 * xv[j];
            }
        }
        __syncthreads();
    }

    bool  valid[3];
    float bias[3];
    #pragma unroll
    for (int i = 0; i < 3; ++i){
        int v = v0 + i * 64 + lane;
        valid[i] = v < VO;
        bias[i]  = valid[i] ? b2[v] : 0.f;
    }
    #pragma unroll
    for (int j = 0; j < 8; ++j){
        const int b = b0 + j;
        float l[3];
        float m = -1e30f;
        #pragma unroll
        for (int i = 0; i < 3; ++i){
            l[i] = acc[i][j] + bias[i];
            if (valid[i]){
                lred[(size_t)b * VO + v0 + i * 64 + lane] = l[i];
                m = fmaxf(m, l[i]);
            }
        }
        float s = 0.f;
        #pragma unroll
        for (int i = 0; i < 3; ++i)
            s += valid[i] ? __expf(l[i] - m) : 0.f;
        #pragma unroll
        for (int off = 1; off < 64; off <<= 1){
            float m2 = __shfl_xor(m, off, 64);
            float s2 = __shfl_xor(s, off, 64);
            float M  = fmaxf(m, m2);
            s = s * __expf(m - M) + s2 * __expf(m2 - M);
            m = M;
        }
        if (lane == 0){
            mch[b * NCHV + blockIdx.x] = m;
            sch[b * NCHV + blockIdx.x] = s;
        }
    }
}

// kC: combine chunk stats in-block, then pf[b][v] = pg[b]/S * exp(lred - M);
// chunk NCH zero-fills the OOV pad
__global__ void kC_final2(const float* __restrict__ lred, const float* __restrict__ mch,
                          const float* __restrict__ sch, const float* __restrict__ pg,
                          float* __restrict__ pf){
    int b = blockIdx.x, c = blockIdx.y, t = threadIdx.x;
    if (c == NCH){
        for (int v = VO + t; v < V; v += 256) pf[(size_t)b * V + v] = 0.f;
        return;
    }
    __shared__ float sm[256], ss[256];
    float m = -1e30f, s = 0.f;
    for (int ch = t; ch < NCHV; ch += 256){
        float mc = mch[b * NCHV + ch], sc = sch[b * NCHV + ch];
        float M = fmaxf(m, mc);
        s = s * __expf(m - M) + sc * __expf(mc - M);
        m = M;
    }
    sm[t] = m; ss[t] = s; __syncthreads();
    for (int o = 128; o > 0; o >>= 1){
        if (t < o){
            float m1 = sm[t], m2 = sm[t + o];
            float M = fmaxf(m1, m2);
            ss[t] = ss[t] * __expf(m1 - M) + ss[t + o] * __expf(m2 - M);
            sm[t] = M;
        }
        __syncthreads();
    }
    float M  = sm[0];
    float sc = pg[b] / ss[0];
    for (int v = c * CHW + t; v < (c + 1) * CHW; v += 256)
        pf[(size_t)b * V + v] = sc * __expf(lred[(size_t)b * VO + v] - M);
}

// K5b: scatter add (1-p_gen)*attn at src indices (32K atomics — negligible)
__global__ void k5b_scatter(const int* __restrict__ src, const float* __restrict__ attn,
                            const float* __restrict__ pg, float* __restrict__ pf){
    int b = blockIdx.x, t = threadIdx.x;
    float c1 = 1.0f - pg[b];
    for (int s = t; s < S; s += 256){
        int idx = src[b * S + s];
        atomicAdd(&pf[(size_t)b * V + idx], c1 * attn[b * S + s]);
    }
}

extern "C" void kernel_launch(void* const* d_in, const int* in_sizes, int n_in,
                              void* d_out, int out_size, void* d_ws, size_t ws_size,
                              hipStream_t stream){
    (void)in_sizes; (void)n_in; (void)out_size; (void)ws_size;
    const float* dec_output = (const float*)d_in[0];
    const float* h          = (const float*)d_in[1];
    const float* c          = (const float*)d_in[2];
    const float* dec_inp    = (const float*)d_in[3];
    const float* enc_op     = (const float*)d_in[4];
    const float* enc_op1    = (const float*)d_in[5];
    const int*   src        = (const int*)d_in[6];
    const float* W_dec      = (const float*)d_in[7];
    const float* b_dec      = (const float*)d_in[8];
    const float* w_attn     = (const float*)d_in[9];
    const float* W_v1       = (const float*)d_in[10];
    const float* b_v1       = (const float*)d_in[11];
    const float* W_v2       = (const float*)d_in[12];
    const float* b_v2       = (const float*)d_in[13];
    const float* W_p        = (const float*)d_in[14];
    const float* b_p        = (const float*)d_in[15];
    const float* bn_g       = (const float*)d_in[16];
    const float* bn_b       = (const float*)d_in[17];
    const float* bn_m       = (const float*)d_in[18];
    const float* bn_v       = (const float*)d_in[19];

    float* ws = (float*)d_ws;
    float* p1       = ws;                    // 32*32768  = 1048576
    float* dec_op1  = ws + 1048576;          // 32768
    float* p3       = ws + 1081344;          // 96*16384  = 1572864
    float* hidden   = ws + 2654208;          // 16384
    float* lred     = ws + 2670592;          // 1568000
    float* attn_lg  = ws + 4238592;          // 32768
    float* ctx_part = ws + 4271360;          // 1048576
    float* pg       = ws + 5319936;          // 32
    float* mch      = ws + 5319968;          // 32*256 = 8192
    float* sch      = ws + 5328160;          // 8192
    float* pm       = ws + 5336352;          // 32*64 = 2048
    float* ps       = ws + 5338400;          // 2048  (total ~20.4 MB)

    float* pf   = (float*)d_out;             // [32,50000]
    float* attn = pf + 1600000;              // [32,1024]
    float* ctx  = pf + 1632768;              // [32,1024]

    // k1: dec_op1 = [h;c] @ W_dec^T  (b_dec folded into k2a), 32 k-splits
    gemm_nt <<<dim3(4, K1SP), 256, 0, stream>>>(W_dec, D2, D2, h, c, D, D, D, p1, 32);
    kreduce <<<128,           256, 0, stream>>>(p1, dec_op1, B * D2, K1SP, nullptr, 0);
    // k2a: logits + per-tile masked softmax partials
    k2a_logit<<<dim3(B, 64),  256, 0, stream>>>(enc_op1, dec_op1, b_dec, w_attn, src,
                                                attn_lg, pm, ps);
    k2c_attn_ctx<<<dim3(B, 32), 256, 0, stream>>>(enc_op, attn_lg, src, pm, ps,
                                                  attn, ctx_part);
    k2d_ctxbn<<<B,            256, 0, stream>>>(ctx_part, bn_g, bn_b, bn_m, bn_v, ctx);
    // k3: hidden = [dec_output;ctx] @ W_v1^T + b_v1, 96 k-splits
    gemm_nt <<<dim3(2, K3SP), 256, 0, stream>>>(W_v1, D, D + D2, dec_output, ctx,
                                                D, D, D2, p3, 16);
    k3r_pgen<<<96,            256, 0, stream>>>(p3, hidden, b_v1,
                                                ctx, h, c, dec_inp, W_p, b_p, pg);
    // k4: lred = hidden @ W_v2^T + b_v2, fused chunk softmax stats (256 blocks)
    gemm_vocab192<<<NCHV,     256, 0, stream>>>(W_v2, hidden, b_v2, lred, mch, sch);
    kC_final2<<<dim3(B, NCH + 1), 256, 0, stream>>>(lred, mch, sch, pg, pf);
    k5b_scatter<<<B,          256, 0, stream>>>(src, attn, pg, pf);
}